// Round 2
// 599.214 us; speedup vs baseline: 1.0139x; 1.0139x over previous
//
#include <hip/hip_runtime.h>

#define G 76
#define GG (G * G)                 // 5776 spatial positions
#define NA 3
#define NC 85
#define TP 64                      // spatial positions per tile
#define NTILES ((GG + TP - 1) / TP) // 91 (90 full + 1 tail of 16)
#define NCH_TOTAL (NA * NC)        // 255

// Native Clang vector type — required by __builtin_nontemporal_load/store
typedef float f32x4 __attribute__((ext_vector_type(4)));

__global__ __launch_bounds__(256) void yolo_decode_kernel(
    const float* __restrict__ in,   // (B, 255, 76, 76)
    const int*   __restrict__ img_dim,
    float*       __restrict__ out)  // (B, 3*5776, 85)
{
    // p-major LDS tile: lds[p*85 + c] -> contiguous in output order
    __shared__ float lds[TP * NC];

    const int tile = blockIdx.x;
    const int a    = blockIdx.y;
    const int b    = blockIdx.z;
    const int tid  = threadIdx.x;

    const int pos0  = tile * TP;
    const int valid = (GG - pos0 < TP) ? (GG - pos0) : TP;  // 64 or 16 (both %4==0)

    const float stride = (float)img_dim[0] / (float)G;       // 8.0
    const float aw = (a == 0) ? 116.0f : (a == 1) ? 156.0f : 373.0f;
    const float ah = (a == 0) ?  90.0f : (a == 1) ? 198.0f : 326.0f;

    // ---- load phase: coalesced nontemporal float4 reads along spatial,
    //      scatter p-major into LDS (streaming data: don't retain in L2/LLC)
    const float* inBase = in + ((size_t)b * NCH_TOTAL + (size_t)a * NC) * GG + pos0;
    const int nvec = NC * (TP / 4);  // 85 * 16 = 1360 float4 chunks
    for (int i = tid; i < nvec; i += 256) {
        const int c  = i >> 4;          // i / 16
        const int p0 = (i & 15) << 2;   // 4-float chunk within the row
        if (p0 < valid) {
            const f32x4 v = __builtin_nontemporal_load(
                (const f32x4*)(inBase + (size_t)c * GG + p0));
            lds[(p0 + 0) * NC + c] = v.x;
            lds[(p0 + 1) * NC + c] = v.y;
            lds[(p0 + 2) * NC + c] = v.z;
            lds[(p0 + 3) * NC + c] = v.w;
        }
    }
    __syncthreads();

    // ---- transform + write phase: contiguous LDS float4 reads,
    //      coalesced nontemporal float4 writes
    float* outBase = out + ((size_t)(b * NA + a) * GG + (size_t)pos0) * NC;
    const int nOut4 = (valid * NC) >> 2;  // 1360 or 340
    for (int i = tid; i < nOut4; i += 256) {
        const int flat = i << 2;
        f32x4 v = *(const f32x4*)&lds[flat];
        float vv[4] = {v.x, v.y, v.z, v.w};
        float rr[4];
#pragma unroll
        for (int j = 0; j < 4; ++j) {
            const unsigned f = (unsigned)(flat + j);
            const unsigned p = f / 85u;            // compiler magic-mul
            const unsigned c = f - 85u * p;
            const int pos = pos0 + (int)p;
            const float x = vv[j];
            const float sig = 1.0f / (1.0f + __expf(-x));
            float r;
            if (c >= 4u) {
                r = sig;                                        // conf + 80 classes
            } else if (c == 0u) {
                r = (sig + (float)(pos % G)) * stride;          // cx
            } else if (c == 1u) {
                r = (sig + (float)(pos / G)) * stride;          // cy
            } else if (c == 2u) {
                r = __expf(x) * aw;                             // w (anchor*stride cancels)
            } else {
                r = __expf(x) * ah;                             // h
            }
            rr[j] = r;
        }
        f32x4 rv;
        rv.x = rr[0]; rv.y = rr[1]; rv.z = rr[2]; rv.w = rr[3];
        __builtin_nontemporal_store(rv, (f32x4*)(outBase + flat));
    }
}

extern "C" void kernel_launch(void* const* d_in, const int* in_sizes, int n_in,
                              void* d_out, int out_size, void* d_ws, size_t ws_size,
                              hipStream_t stream) {
    const float* x       = (const float*)d_in[0];
    const int*   img_dim = (const int*)d_in[1];
    float*       out     = (float*)d_out;

    const int B = in_sizes[0] / (NCH_TOTAL * GG);  // 64

    dim3 grid(NTILES, NA, B);  // 91 x 3 x 64 = 17472 blocks
    dim3 block(256);
    yolo_decode_kernel<<<grid, block, 0, stream>>>(x, img_dim, out);
}